// Round 12
// baseline (217.576 us; speedup 1.0000x reference)
//
#include <hip/hip_runtime.h>

#define DIM 256
#define NSB 8
#define NLBL 64
#define NSEG (NSB * NLBL)
#define NBH 128   // histogram blocks
#define CAP 576   // staged rows per segment (LDS int8)
// dynamic LDS: xrows CAP*256B + muA 256*4 + wsum 16*4
#define SMEM_BYTES (CAP * 256 + DIM * 4 + 16 * 4)

// ---------------- k1: per-block histogram (plain stores) ----------------
__global__ void k_hist(const int* __restrict__ labels, const int* __restrict__ sbidx,
                       int* __restrict__ blockBins, int n) {
    __shared__ int bins[NSEG];
    for (int i = threadIdx.x; i < NSEG; i += 256) bins[i] = 0;
    __syncthreads();
    int t4 = blockIdx.x * 256 + threadIdx.x;
    int stride4 = gridDim.x * 256;
    for (int q = t4; q * 4 < n; q += stride4) {
        int4 lb = reinterpret_cast<const int4*>(labels)[q];
        int4 sb = reinterpret_cast<const int4*>(sbidx)[q];
        atomicAdd(&bins[sb.x * NLBL + lb.x], 1);
        atomicAdd(&bins[sb.y * NLBL + lb.y], 1);
        atomicAdd(&bins[sb.z * NLBL + lb.z], 1);
        atomicAdd(&bins[sb.w * NLBL + lb.w], 1);
    }
    __syncthreads();
    for (int i = threadIdx.x; i < NSEG; i += 256)
        blockBins[blockIdx.x * NSEG + i] = bins[i];
}

// ---------------- k2: reduce bins + scan + zero small accumulators ----------------
__global__ void k_scan(const int* __restrict__ blockBins, int* __restrict__ counts,
                       int* __restrict__ offsets, int* __restrict__ cursors,
                       float* __restrict__ Mvals, float* __restrict__ invcnt,
                       float* __restrict__ Lpull, float* __restrict__ pushv,
                       int* __restrict__ ticket) {
    __shared__ int cnt[NSEG];
    int t = threadIdx.x;          // 512 threads, one per segment
    int sum = 0;
    #pragma unroll 8
    for (int b = 0; b < NBH; b++) sum += blockBins[b * NSEG + t];
    cnt[t] = sum;
    counts[t] = sum;
    invcnt[t] = 1.0f / fmaxf((float)sum, 1.0f);
    if (t < NSB) { Lpull[t] = 0.f; pushv[t] = 0.f; }
    if (t == 0) ticket[0] = 0;    // re-zeroed every run: graph-replay-safe
    __syncthreads();
    if (t < 64) {                 // exclusive scan over 512 counts, one wave
        int lane = t;
        int carry = 0;
        for (int c = 0; c < NSB; c++) {
            int idx = c * 64 + lane;
            int v = cnt[idx];
            int incl = v;
            #pragma unroll
            for (int m = 1; m < 64; m <<= 1) {
                int t2 = __shfl_up(incl, m, 64);
                if (lane >= m) incl += t2;
            }
            int excl = carry + incl - v;
            offsets[idx] = excl;
            cursors[idx] = excl;
            carry += __shfl(incl, 63, 64);
            unsigned long long b = __ballot(v > 0);
            if (lane == 0) Mvals[c] = (float)__popcll(b);
        }
    }
}

// ---------------- k3: scatter point INDICES into sorted order (4B, proven fast) ----------------
__global__ void k_scatter(const int* __restrict__ labels, const int* __restrict__ sbidx,
                          int* __restrict__ cursors, int* __restrict__ sorted, int n) {
    int t = blockIdx.x * blockDim.x + threadIdx.x;
    int stride = gridDim.x * blockDim.x;
    for (int q = t; q * 4 < n; q += stride) {
        int4 lb = reinterpret_cast<const int4*>(labels)[q];
        int4 sb = reinterpret_cast<const int4*>(sbidx)[q];
        int p = q * 4;
        sorted[atomicAdd(&cursors[sb.x * NLBL + lb.x], 1)] = p;
        sorted[atomicAdd(&cursors[sb.y * NLBL + lb.y], 1)] = p + 1;
        sorted[atomicAdd(&cursors[sb.z * NLBL + lb.z], 1)] = p + 2;
        sorted[atomicAdd(&cursors[sb.w * NLBL + lb.w], 1)] = p + 3;
    }
}

__device__ inline unsigned packq(float x, float y, float z, float w, float s) {
    int q0 = (int)rintf(x * s); q0 = max(-127, min(127, q0));
    int q1 = (int)rintf(y * s); q1 = max(-127, min(127, q1));
    int q2 = (int)rintf(z * s); q2 = max(-127, min(127, q2));
    int q3 = (int)rintf(w * s); q3 = max(-127, min(127, q3));
    return (unsigned)(q0 & 255) | ((unsigned)(q1 & 255) << 8) |
           ((unsigned)(q2 & 255) << 16) | ((unsigned)(q3 & 255) << 24);
}

// ------- k4: natural-order stream, 8-deep ILP: normalize + pack int8, coalesced write -------
__global__ void k_norm(const float* __restrict__ outp, unsigned* __restrict__ xns, int n) {
    int w = (blockIdx.x * blockDim.x + threadIdx.x) >> 6;
    int lane = threadIdx.x & 63;
    int nw = (gridDim.x * blockDim.x) >> 6;
    for (int pb = w * 8; pb < n; pb += nw * 8) {
        bool c1 = pb + 1 < n, c2 = pb + 2 < n, c3 = pb + 3 < n;
        bool c4 = pb + 4 < n, c5 = pb + 5 < n, c6 = pb + 6 < n, c7 = pb + 7 < n;
        float4 z = {0.f,0.f,0.f,0.f};
        float4 v0 = *reinterpret_cast<const float4*>(outp + (size_t)(pb + 0) * DIM + lane * 4);
        float4 v1 = c1 ? *reinterpret_cast<const float4*>(outp + (size_t)(pb + 1) * DIM + lane * 4) : z;
        float4 v2 = c2 ? *reinterpret_cast<const float4*>(outp + (size_t)(pb + 2) * DIM + lane * 4) : z;
        float4 v3 = c3 ? *reinterpret_cast<const float4*>(outp + (size_t)(pb + 3) * DIM + lane * 4) : z;
        float4 v4 = c4 ? *reinterpret_cast<const float4*>(outp + (size_t)(pb + 4) * DIM + lane * 4) : z;
        float4 v5 = c5 ? *reinterpret_cast<const float4*>(outp + (size_t)(pb + 5) * DIM + lane * 4) : z;
        float4 v6 = c6 ? *reinterpret_cast<const float4*>(outp + (size_t)(pb + 6) * DIM + lane * 4) : z;
        float4 v7 = c7 ? *reinterpret_cast<const float4*>(outp + (size_t)(pb + 7) * DIM + lane * 4) : z;
        float s0 = v0.x*v0.x + v0.y*v0.y + v0.z*v0.z + v0.w*v0.w;
        float s1 = v1.x*v1.x + v1.y*v1.y + v1.z*v1.z + v1.w*v1.w;
        float s2 = v2.x*v2.x + v2.y*v2.y + v2.z*v2.z + v2.w*v2.w;
        float s3 = v3.x*v3.x + v3.y*v3.y + v3.z*v3.z + v3.w*v3.w;
        float s4 = v4.x*v4.x + v4.y*v4.y + v4.z*v4.z + v4.w*v4.w;
        float s5 = v5.x*v5.x + v5.y*v5.y + v5.z*v5.z + v5.w*v5.w;
        float s6 = v6.x*v6.x + v6.y*v6.y + v6.z*v6.z + v6.w*v6.w;
        float s7 = v7.x*v7.x + v7.y*v7.y + v7.z*v7.z + v7.w*v7.w;
        #pragma unroll
        for (int m = 32; m >= 1; m >>= 1) {   // 8 interleaved trees
            s0 += __shfl_xor(s0, m, 64); s1 += __shfl_xor(s1, m, 64);
            s2 += __shfl_xor(s2, m, 64); s3 += __shfl_xor(s3, m, 64);
            s4 += __shfl_xor(s4, m, 64); s5 += __shfl_xor(s5, m, 64);
            s6 += __shfl_xor(s6, m, 64); s7 += __shfl_xor(s7, m, 64);
        }
        float r0 = 256.0f / (sqrtf(s0) + 1e-8f);
        float r1 = 256.0f / (sqrtf(s1) + 1e-8f);
        float r2 = 256.0f / (sqrtf(s2) + 1e-8f);
        float r3 = 256.0f / (sqrtf(s3) + 1e-8f);
        float r4 = 256.0f / (sqrtf(s4) + 1e-8f);
        float r5 = 256.0f / (sqrtf(s5) + 1e-8f);
        float r6 = 256.0f / (sqrtf(s6) + 1e-8f);
        float r7 = 256.0f / (sqrtf(s7) + 1e-8f);
        xns[(size_t)(pb + 0) * 64 + lane] = packq(v0.x, v0.y, v0.z, v0.w, r0);
        if (c1) xns[(size_t)(pb + 1) * 64 + lane] = packq(v1.x, v1.y, v1.z, v1.w, r1);
        if (c2) xns[(size_t)(pb + 2) * 64 + lane] = packq(v2.x, v2.y, v2.z, v2.w, r2);
        if (c3) xns[(size_t)(pb + 3) * 64 + lane] = packq(v3.x, v3.y, v3.z, v3.w, r3);
        if (c4) xns[(size_t)(pb + 4) * 64 + lane] = packq(v4.x, v4.y, v4.z, v4.w, r4);
        if (c5) xns[(size_t)(pb + 5) * 64 + lane] = packq(v5.x, v5.y, v5.z, v5.w, r5);
        if (c6) xns[(size_t)(pb + 6) * 64 + lane] = packq(v6.x, v6.y, v6.z, v6.w, r6);
        if (c7) xns[(size_t)(pb + 7) * 64 + lane] = packq(v7.x, v7.y, v7.z, v7.w, r7);
    }
}

// ------- k5: per-segment block: gather int8 rows (L3-resident), 8-deep, int mu-accum, LDS pull -------
__global__ __launch_bounds__(1024) void k_seg(
    const unsigned* __restrict__ xns, const int* __restrict__ sorted,
    const int* __restrict__ offsets, const int* __restrict__ counts,
    const float* __restrict__ invcnt, float* __restrict__ mus,
    float* __restrict__ Lpull) {
    extern __shared__ unsigned char smem[];
    unsigned* xrows = (unsigned*)smem;                   // CAP rows * 64 dwords
    int* muI    = (int*)(smem + CAP * 256);              // 256 (atomic int accum, q units)
    float* muA  = (float*)(smem + CAP * 256);            // aliased after conversion
    float* wsum = (float*)(smem + CAP * 256 + DIM * 4);  // 16

    int seg = blockIdx.x;
    int base = offsets[seg], cnt = counts[seg];
    int tid = threadIdx.x, lane = tid & 63, wv = tid >> 6;   // 16 waves
    float ic = invcnt[seg];
    if (tid < DIM) muI[tid] = 0;
    __syncthreads();
    if (cnt == 0) {
        if (tid < DIM) mus[(size_t)seg * DIM + tid] = 0.f;
        return;
    }

    // ---- Phase A: gather int8 rows via sorted ids, 8-deep; int accumulate; stage into LDS ----
    int4 acc = {0, 0, 0, 0};
    int r = wv * 8;
    int p0 = (r + 0 < cnt) ? sorted[base + r + 0] : -1;
    int p1 = (r + 1 < cnt) ? sorted[base + r + 1] : -1;
    int p2 = (r + 2 < cnt) ? sorted[base + r + 2] : -1;
    int p3 = (r + 3 < cnt) ? sorted[base + r + 3] : -1;
    int p4 = (r + 4 < cnt) ? sorted[base + r + 4] : -1;
    int p5 = (r + 5 < cnt) ? sorted[base + r + 5] : -1;
    int p6 = (r + 6 < cnt) ? sorted[base + r + 6] : -1;
    int p7 = (r + 7 < cnt) ? sorted[base + r + 7] : -1;
    for (; r < cnt; r += 128) {
        int nr = r + 128;
        int q0 = (nr + 0 < cnt) ? sorted[base + nr + 0] : -1;   // prefetch next ids
        int q1 = (nr + 1 < cnt) ? sorted[base + nr + 1] : -1;
        int q2 = (nr + 2 < cnt) ? sorted[base + nr + 2] : -1;
        int q3 = (nr + 3 < cnt) ? sorted[base + nr + 3] : -1;
        int q4 = (nr + 4 < cnt) ? sorted[base + nr + 4] : -1;
        int q5 = (nr + 5 < cnt) ? sorted[base + nr + 5] : -1;
        int q6 = (nr + 6 < cnt) ? sorted[base + nr + 6] : -1;
        int q7 = (nr + 7 < cnt) ? sorted[base + nr + 7] : -1;
        unsigned w0 = xns[(size_t)p0 * 64 + lane];
        unsigned w1 = (p1 >= 0) ? xns[(size_t)p1 * 64 + lane] : 0u;
        unsigned w2 = (p2 >= 0) ? xns[(size_t)p2 * 64 + lane] : 0u;
        unsigned w3 = (p3 >= 0) ? xns[(size_t)p3 * 64 + lane] : 0u;
        unsigned w4 = (p4 >= 0) ? xns[(size_t)p4 * 64 + lane] : 0u;
        unsigned w5 = (p5 >= 0) ? xns[(size_t)p5 * 64 + lane] : 0u;
        unsigned w6 = (p6 >= 0) ? xns[(size_t)p6 * 64 + lane] : 0u;
        unsigned w7 = (p7 >= 0) ? xns[(size_t)p7 * 64 + lane] : 0u;
        if (r + 0 < CAP)            xrows[(r + 0) * 64 + lane] = w0;
        if (p1 >= 0 && r + 1 < CAP) xrows[(r + 1) * 64 + lane] = w1;
        if (p2 >= 0 && r + 2 < CAP) xrows[(r + 2) * 64 + lane] = w2;
        if (p3 >= 0 && r + 3 < CAP) xrows[(r + 3) * 64 + lane] = w3;
        if (p4 >= 0 && r + 4 < CAP) xrows[(r + 4) * 64 + lane] = w4;
        if (p5 >= 0 && r + 5 < CAP) xrows[(r + 5) * 64 + lane] = w5;
        if (p6 >= 0 && r + 6 < CAP) xrows[(r + 6) * 64 + lane] = w6;
        if (p7 >= 0 && r + 7 < CAP) xrows[(r + 7) * 64 + lane] = w7;
        acc.x += ((int)(w0 << 24) >> 24) + ((int)(w1 << 24) >> 24) +
                 ((int)(w2 << 24) >> 24) + ((int)(w3 << 24) >> 24) +
                 ((int)(w4 << 24) >> 24) + ((int)(w5 << 24) >> 24) +
                 ((int)(w6 << 24) >> 24) + ((int)(w7 << 24) >> 24);
        acc.y += ((int)(w0 << 16) >> 24) + ((int)(w1 << 16) >> 24) +
                 ((int)(w2 << 16) >> 24) + ((int)(w3 << 16) >> 24) +
                 ((int)(w4 << 16) >> 24) + ((int)(w5 << 16) >> 24) +
                 ((int)(w6 << 16) >> 24) + ((int)(w7 << 16) >> 24);
        acc.z += ((int)(w0 <<  8) >> 24) + ((int)(w1 <<  8) >> 24) +
                 ((int)(w2 <<  8) >> 24) + ((int)(w3 <<  8) >> 24) +
                 ((int)(w4 <<  8) >> 24) + ((int)(w5 <<  8) >> 24) +
                 ((int)(w6 <<  8) >> 24) + ((int)(w7 <<  8) >> 24);
        acc.w += ((int)w0 >> 24) + ((int)w1 >> 24) + ((int)w2 >> 24) + ((int)w3 >> 24) +
                 ((int)w4 >> 24) + ((int)w5 >> 24) + ((int)w6 >> 24) + ((int)w7 >> 24);
        p0 = q0; p1 = q1; p2 = q2; p3 = q3; p4 = q4; p5 = q5; p6 = q6; p7 = q7;
    }
    atomicAdd(&muI[lane * 4 + 0], acc.x);
    atomicAdd(&muI[lane * 4 + 1], acc.y);
    atomicAdd(&muI[lane * 4 + 2], acc.z);
    atomicAdd(&muI[lane * 4 + 3], acc.w);
    __syncthreads();
    if (tid < DIM) {
        float t = (float)muI[tid];
        mus[(size_t)seg * DIM + tid] = t * ic * 0.00390625f;   // real units for push
        muA[tid] = t * ic;                                      // q units (mu*256)
    }
    __syncthreads();

    // ---- Phase B: pull from LDS (int8), mu256 in registers ----
    float4 mu256 = *reinterpret_cast<const float4*>(muA + lane * 4);
    float psum = 0.f;
    int m1 = min(cnt, CAP);
    for (int rr = wv * 4; rr < m1; rr += 64) {
        bool b1 = rr + 1 < m1, b2 = rr + 2 < m1, b3 = rr + 3 < m1;
        unsigned w0 = xrows[(rr + 0) * 64 + lane];
        unsigned w1 = b1 ? xrows[(rr + 1) * 64 + lane] : 0u;
        unsigned w2 = b2 ? xrows[(rr + 2) * 64 + lane] : 0u;
        unsigned w3 = b3 ? xrows[(rr + 3) * 64 + lane] : 0u;
        float d0 = fabsf(mu256.x - (float)((int)(w0 << 24) >> 24))
                 + fabsf(mu256.y - (float)((int)(w0 << 16) >> 24))
                 + fabsf(mu256.z - (float)((int)(w0 <<  8) >> 24))
                 + fabsf(mu256.w - (float)((int)w0 >> 24));
        float d1 = fabsf(mu256.x - (float)((int)(w1 << 24) >> 24))
                 + fabsf(mu256.y - (float)((int)(w1 << 16) >> 24))
                 + fabsf(mu256.z - (float)((int)(w1 <<  8) >> 24))
                 + fabsf(mu256.w - (float)((int)w1 >> 24));
        float d2 = fabsf(mu256.x - (float)((int)(w2 << 24) >> 24))
                 + fabsf(mu256.y - (float)((int)(w2 << 16) >> 24))
                 + fabsf(mu256.z - (float)((int)(w2 <<  8) >> 24))
                 + fabsf(mu256.w - (float)((int)w2 >> 24));
        float d3 = fabsf(mu256.x - (float)((int)(w3 << 24) >> 24))
                 + fabsf(mu256.y - (float)((int)(w3 << 16) >> 24))
                 + fabsf(mu256.z - (float)((int)(w3 <<  8) >> 24))
                 + fabsf(mu256.w - (float)((int)w3 >> 24));
        #pragma unroll
        for (int m = 32; m >= 1; m >>= 1) {   // 4 interleaved trees
            d0 += __shfl_xor(d0, m, 64);
            d1 += __shfl_xor(d1, m, 64);
            d2 += __shfl_xor(d2, m, 64);
            d3 += __shfl_xor(d3, m, 64);
        }
        float t0 = fmaxf(d0 * 0.00390625f - 0.5f, 0.f);   // /256, DELTA_V
        psum += t0 * t0;
        if (b1) { float t = fmaxf(d1 * 0.00390625f - 0.5f, 0.f); psum += t * t; }
        if (b2) { float t = fmaxf(d2 * 0.00390625f - 0.5f, 0.f); psum += t * t; }
        if (b3) { float t = fmaxf(d3 * 0.00390625f - 0.5f, 0.f); psum += t * t; }
    }
    // overflow rows (cnt > CAP): gather from global xns (L3-resident, rare)
    for (int rr = CAP + wv; rr < cnt; rr += 16) {
        int p = sorted[base + rr];
        unsigned w0 = xns[(size_t)p * 64 + lane];
        float d = fabsf(mu256.x - (float)((int)(w0 << 24) >> 24))
                + fabsf(mu256.y - (float)((int)(w0 << 16) >> 24))
                + fabsf(mu256.z - (float)((int)(w0 <<  8) >> 24))
                + fabsf(mu256.w - (float)((int)w0 >> 24));
        #pragma unroll
        for (int m = 32; m >= 1; m >>= 1) d += __shfl_xor(d, m, 64);
        float t = fmaxf(d * 0.00390625f - 0.5f, 0.f);
        psum += t * t;
    }
    if (lane == 0) wsum[wv] = psum;
    __syncthreads();
    if (tid == 0) {
        float tot = 0.f;
        #pragma unroll
        for (int w = 0; w < 16; w++) tot += wsum[w];
        atomicAdd(&Lpull[seg >> 6], tot * ic);
    }
}

// ---------------- k6: push (128 blocks) + ticketed final combine ----------------
__global__ void k_final(const float* __restrict__ mus, const int* __restrict__ counts,
                        float* __restrict__ pushv, float* __restrict__ Lpull,
                        const float* __restrict__ Mvals, int* __restrict__ ticket,
                        float* __restrict__ outv, int n) {
    __shared__ float lds[NLBL][DIM + 1];
    __shared__ float wsum[4];
    __shared__ int lastFlag;
    int s = blockIdx.x >> 4;
    int chunk = blockIdx.x & 15;
    for (int i = threadIdx.x; i < NLBL * DIM; i += 256) {
        int r = i >> 8, d = i & 255;
        lds[r][d] = mus[(size_t)(s * NLBL + r) * DIM + d];
    }
    __syncthreads();
    int pair = chunk * 256 + threadIdx.x;
    int l1 = pair >> 6, l2 = pair & 63;
    float dist = 0.0f;
    #pragma unroll 8
    for (int d = 0; d < DIM; d++) dist += fabsf(lds[l1][d] - lds[l2][d]);
    float v = fmaxf(3.0f - dist, 0.0f);   // 2*DELTA_D
    v = v * v;
    bool ok = (l1 != l2) && (counts[s * NLBL + l1] > 0) && (counts[s * NLBL + l2] > 0);
    v = ok ? v : 0.0f;
    #pragma unroll
    for (int m = 32; m >= 1; m >>= 1) v += __shfl_xor(v, m, 64);
    if ((threadIdx.x & 63) == 0) wsum[threadIdx.x >> 6] = v;
    __syncthreads();
    if (threadIdx.x == 0) {
        atomicAdd(&pushv[s], wsum[0] + wsum[1] + wsum[2] + wsum[3]);
        __threadfence();
        int t = atomicAdd(ticket, 1);
        lastFlag = (t == (int)gridDim.x - 1) ? 1 : 0;
    }
    __syncthreads();
    if (lastFlag && threadIdx.x == 0) {
        float loss = 0.0f;
        for (int q = 0; q < NSB; q++) {
            float M = Mvals[q];
            float pv = atomicAdd(&pushv[q], 0.0f);    // coherent cross-XCD read
            float lpv = atomicAdd(&Lpull[q], 0.0f);
            if (M > 1.0f)
                loss += lpv / M + pv / fmaxf(M * (M - 1.0f), 1.0f);
        }
        outv[0] = loss / (float)n;
    }
}

extern "C" void kernel_launch(void* const* d_in, const int* in_sizes, int n_in,
                              void* d_out, int out_size, void* d_ws, size_t ws_size,
                              hipStream_t stream) {
    const float* outp = (const float*)d_in[0];
    const int* labels = (const int*)d_in[1];
    const int* sbidx = (const int*)d_in[2];
    float* outv = (float*)d_out;
    int n = in_sizes[1];

    // workspace layout
    unsigned* xns = (unsigned*)d_ws;                      // n*64 dwords (67 MB), NATURAL order
    float* mus = (float*)(xns + (size_t)n * 64);          // NSEG*DIM
    int* sorted = (int*)(mus + (size_t)NSEG * DIM);       // n
    int* blockBins = sorted + n;                          // NBH*NSEG
    int* counts = blockBins + NBH * NSEG;                 // 512
    int* offsets = counts + NSEG;                         // 512
    int* cursors = offsets + NSEG;                        // 512
    int* ticket = cursors + NSEG;                         // 1
    float* invcnt = (float*)(ticket + 1);                 // 512
    float* Mvals = invcnt + NSEG;                         // 8
    float* Lpull = Mvals + NSB;                           // 8
    float* pushv = Lpull + NSB;                           // 8

    hipFuncSetAttribute(reinterpret_cast<const void*>(k_seg),
                        hipFuncAttributeMaxDynamicSharedMemorySize, SMEM_BYTES);

    k_hist<<<NBH, 256, 0, stream>>>(labels, sbidx, blockBins, n);
    k_scan<<<1, 512, 0, stream>>>(blockBins, counts, offsets, cursors, Mvals, invcnt,
                                  Lpull, pushv, ticket);
    k_scatter<<<256, 256, 0, stream>>>(labels, sbidx, cursors, sorted, n);
    k_norm<<<2048, 256, 0, stream>>>(outp, xns, n);
    k_seg<<<NSEG, 1024, SMEM_BYTES, stream>>>(xns, sorted, offsets, counts, invcnt,
                                              mus, Lpull);
    k_final<<<NSB * 16, 256, 0, stream>>>(mus, counts, pushv, Lpull, Mvals,
                                          ticket, outv, n);
}

// Round 13
// 209.882 us; speedup vs baseline: 1.0367x; 1.0367x over previous
//
#include <hip/hip_runtime.h>

#define DIM 256
#define NSB 8
#define NLBL 64
#define NSEG (NSB * NLBL)
#define NBH 128   // histogram blocks

// ---------------- k1: per-block histogram (plain stores) ----------------
__global__ void k_hist(const int* __restrict__ labels, const int* __restrict__ sbidx,
                       int* __restrict__ blockBins, int n) {
    __shared__ int bins[NSEG];
    for (int i = threadIdx.x; i < NSEG; i += 256) bins[i] = 0;
    __syncthreads();
    int t4 = blockIdx.x * 256 + threadIdx.x;
    int stride4 = gridDim.x * 256;
    for (int q = t4; q * 4 < n; q += stride4) {
        int4 lb = reinterpret_cast<const int4*>(labels)[q];
        int4 sb = reinterpret_cast<const int4*>(sbidx)[q];
        atomicAdd(&bins[sb.x * NLBL + lb.x], 1);
        atomicAdd(&bins[sb.y * NLBL + lb.y], 1);
        atomicAdd(&bins[sb.z * NLBL + lb.z], 1);
        atomicAdd(&bins[sb.w * NLBL + lb.w], 1);
    }
    __syncthreads();
    for (int i = threadIdx.x; i < NSEG; i += 256)
        blockBins[blockIdx.x * NSEG + i] = bins[i];
}

// ------- k2: reduce bins + scan over 64-ALIGNED capacities + zero small accumulators -------
__global__ void k_scan(const int* __restrict__ blockBins, int* __restrict__ counts,
                       int* __restrict__ offsets, int* __restrict__ cursors,
                       float* __restrict__ Mvals, float* __restrict__ invcnt,
                       float* __restrict__ Lpull, float* __restrict__ pushv,
                       int* __restrict__ ticket) {
    __shared__ int cnt[NSEG];
    int t = threadIdx.x;          // 512 threads, one per segment
    int sum = 0;
    #pragma unroll 8
    for (int b = 0; b < NBH; b++) sum += blockBins[b * NSEG + t];
    cnt[t] = sum;
    counts[t] = sum;
    invcnt[t] = 1.0f / fmaxf((float)sum, 1.0f);
    if (t < NSB) { Lpull[t] = 0.f; pushv[t] = 0.f; }
    if (t == 0) ticket[0] = 0;    // re-zeroed every run: graph-replay-safe
    __syncthreads();
    if (t < 64) {                 // exclusive scan over 512 ALIGNED capacities, one wave
        int lane = t;
        int carry = 0;
        for (int c = 0; c < NSB; c++) {
            int idx = c * 64 + lane;
            int v = cnt[idx];
            int vr = (v + 63) & ~63;   // 64-row aligned capacity
            int incl = vr;
            #pragma unroll
            for (int m = 1; m < 64; m <<= 1) {
                int t2 = __shfl_up(incl, m, 64);
                if (lane >= m) incl += t2;
            }
            int excl = carry + incl - vr;
            offsets[idx] = excl;
            cursors[idx] = excl;
            carry += __shfl(incl, 63, 64);
            unsigned long long b = __ballot(v > 0);
            if (lane == 0) Mvals[c] = (float)__popcll(b);
        }
    }
}

// ---------------- k3: scatter point INDICES into aligned sorted slots ----------------
__global__ void k_scatter(const int* __restrict__ labels, const int* __restrict__ sbidx,
                          int* __restrict__ cursors, int* __restrict__ sorted, int n) {
    int t = blockIdx.x * blockDim.x + threadIdx.x;
    int stride = gridDim.x * blockDim.x;
    for (int q = t; q * 4 < n; q += stride) {
        int4 lb = reinterpret_cast<const int4*>(labels)[q];
        int4 sb = reinterpret_cast<const int4*>(sbidx)[q];
        int p = q * 4;
        sorted[atomicAdd(&cursors[sb.x * NLBL + lb.x], 1)] = p;
        sorted[atomicAdd(&cursors[sb.y * NLBL + lb.y], 1)] = p + 1;
        sorted[atomicAdd(&cursors[sb.z * NLBL + lb.z], 1)] = p + 2;
        sorted[atomicAdd(&cursors[sb.w * NLBL + lb.w], 1)] = p + 3;
    }
}

__device__ inline unsigned packq(float x, float y, float z, float w, float s) {
    int q0 = (int)rintf(x * s); q0 = max(-127, min(127, q0));
    int q1 = (int)rintf(y * s); q1 = max(-127, min(127, q1));
    int q2 = (int)rintf(z * s); q2 = max(-127, min(127, q2));
    int q3 = (int)rintf(w * s); q3 = max(-127, min(127, q3));
    return (unsigned)(q0 & 255) | ((unsigned)(q1 & 255) << 8) |
           ((unsigned)(q2 & 255) << 16) | ((unsigned)(q3 & 255) << 24);
}

// ------- k4: one 16-wave block per segment, ~2KB LDS, 2 blocks/CU.
// Phase A: unconditional f32 gather -> mu (LDS atomics) + int8 row -> global xq (own range).
// Phase B: same wave re-reads ITS OWN xq rows (L1/L2-hot), computes pull. -------
__global__ __launch_bounds__(1024, 8) void k_seg(
    const float* __restrict__ outp, const int* __restrict__ sorted,
    const int* __restrict__ offsets, const int* __restrict__ counts,
    const float* __restrict__ invcnt, unsigned* __restrict__ xq,
    float* __restrict__ mus, float* __restrict__ Lpull, int n) {
    __shared__ float muA[DIM];
    __shared__ float wsum[16];
    int seg = blockIdx.x;
    int base = offsets[seg], cnt = counts[seg];
    int cntR = (cnt + 63) & ~63;
    int tid = threadIdx.x, lane = tid & 63, wv = tid >> 6;   // 16 waves
    float ic = invcnt[seg];
    unsigned pmax = (unsigned)(n - 1);
    if (tid < DIM) muA[tid] = 0.f;
    __syncthreads();

    // ---- Phase A ----
    float ax = 0.f, ay = 0.f, az = 0.f, aw = 0.f;   // q-unit accumulators
    for (int r = wv * 4; r < cntR; r += 64) {
        int4 id4 = *reinterpret_cast<const int4*>(sorted + base + r);  // 16B-aligned
        unsigned p0 = min((unsigned)id4.x, pmax);
        unsigned p1 = min((unsigned)id4.y, pmax);
        unsigned p2 = min((unsigned)id4.z, pmax);
        unsigned p3 = min((unsigned)id4.w, pmax);
        float w0 = (r + 0 < cnt) ? 1.f : 0.f;
        float w1 = (r + 1 < cnt) ? 1.f : 0.f;
        float w2 = (r + 2 < cnt) ? 1.f : 0.f;
        float w3 = (r + 3 < cnt) ? 1.f : 0.f;
        float4 v0 = *reinterpret_cast<const float4*>(outp + (size_t)p0 * DIM + lane * 4);
        float4 v1 = *reinterpret_cast<const float4*>(outp + (size_t)p1 * DIM + lane * 4);
        float4 v2 = *reinterpret_cast<const float4*>(outp + (size_t)p2 * DIM + lane * 4);
        float4 v3 = *reinterpret_cast<const float4*>(outp + (size_t)p3 * DIM + lane * 4);
        float s0 = v0.x*v0.x + v0.y*v0.y + v0.z*v0.z + v0.w*v0.w;
        float s1 = v1.x*v1.x + v1.y*v1.y + v1.z*v1.z + v1.w*v1.w;
        float s2 = v2.x*v2.x + v2.y*v2.y + v2.z*v2.z + v2.w*v2.w;
        float s3 = v3.x*v3.x + v3.y*v3.y + v3.z*v3.z + v3.w*v3.w;
        #pragma unroll
        for (int m = 32; m >= 1; m >>= 1) {   // 4 interleaved trees
            s0 += __shfl_xor(s0, m, 64);
            s1 += __shfl_xor(s1, m, 64);
            s2 += __shfl_xor(s2, m, 64);
            s3 += __shfl_xor(s3, m, 64);
        }
        float r0 = 256.0f / (sqrtf(s0) + 1e-8f);   // q-unit scale
        float r1 = 256.0f / (sqrtf(s1) + 1e-8f);
        float r2 = 256.0f / (sqrtf(s2) + 1e-8f);
        float r3 = 256.0f / (sqrtf(s3) + 1e-8f);
        xq[(size_t)(base + r + 0) * 64 + lane] = packq(v0.x, v0.y, v0.z, v0.w, r0);
        xq[(size_t)(base + r + 1) * 64 + lane] = packq(v1.x, v1.y, v1.z, v1.w, r1);
        xq[(size_t)(base + r + 2) * 64 + lane] = packq(v2.x, v2.y, v2.z, v2.w, r2);
        xq[(size_t)(base + r + 3) * 64 + lane] = packq(v3.x, v3.y, v3.z, v3.w, r3);
        float f0 = r0 * w0, f1 = r1 * w1, f2 = r2 * w2, f3 = r3 * w3;
        ax += v0.x*f0 + v1.x*f1 + v2.x*f2 + v3.x*f3;
        ay += v0.y*f0 + v1.y*f1 + v2.y*f2 + v3.y*f3;
        az += v0.z*f0 + v1.z*f1 + v2.z*f2 + v3.z*f3;
        aw += v0.w*f0 + v1.w*f1 + v2.w*f2 + v3.w*f3;
    }
    atomicAdd(&muA[lane * 4 + 0], ax);
    atomicAdd(&muA[lane * 4 + 1], ay);
    atomicAdd(&muA[lane * 4 + 2], az);
    atomicAdd(&muA[lane * 4 + 3], aw);
    __syncthreads();
    if (tid < DIM) {
        float s = muA[tid] * ic;                       // q units
        mus[(size_t)seg * DIM + tid] = s * 0.00390625f; // real units for push
        muA[tid] = s;
    }
    __syncthreads();

    // ---- Phase B: re-read own int8 rows (L1/L2-hot), pull term ----
    float4 mu256 = *reinterpret_cast<const float4*>(muA + lane * 4);
    float psum = 0.f;
    for (int r = wv * 4; r < cntR; r += 64) {
        unsigned w0 = xq[(size_t)(base + r + 0) * 64 + lane];
        unsigned w1 = xq[(size_t)(base + r + 1) * 64 + lane];
        unsigned w2 = xq[(size_t)(base + r + 2) * 64 + lane];
        unsigned w3 = xq[(size_t)(base + r + 3) * 64 + lane];
        float d0 = fabsf(mu256.x - (float)((int)(w0 << 24) >> 24))
                 + fabsf(mu256.y - (float)((int)(w0 << 16) >> 24))
                 + fabsf(mu256.z - (float)((int)(w0 <<  8) >> 24))
                 + fabsf(mu256.w - (float)((int)w0 >> 24));
        float d1 = fabsf(mu256.x - (float)((int)(w1 << 24) >> 24))
                 + fabsf(mu256.y - (float)((int)(w1 << 16) >> 24))
                 + fabsf(mu256.z - (float)((int)(w1 <<  8) >> 24))
                 + fabsf(mu256.w - (float)((int)w1 >> 24));
        float d2 = fabsf(mu256.x - (float)((int)(w2 << 24) >> 24))
                 + fabsf(mu256.y - (float)((int)(w2 << 16) >> 24))
                 + fabsf(mu256.z - (float)((int)(w2 <<  8) >> 24))
                 + fabsf(mu256.w - (float)((int)w2 >> 24));
        float d3 = fabsf(mu256.x - (float)((int)(w3 << 24) >> 24))
                 + fabsf(mu256.y - (float)((int)(w3 << 16) >> 24))
                 + fabsf(mu256.z - (float)((int)(w3 <<  8) >> 24))
                 + fabsf(mu256.w - (float)((int)w3 >> 24));
        #pragma unroll
        for (int m = 32; m >= 1; m >>= 1) {   // 4 interleaved trees
            d0 += __shfl_xor(d0, m, 64);
            d1 += __shfl_xor(d1, m, 64);
            d2 += __shfl_xor(d2, m, 64);
            d3 += __shfl_xor(d3, m, 64);
        }
        float u0 = (r + 0 < cnt) ? 1.f : 0.f;
        float u1 = (r + 1 < cnt) ? 1.f : 0.f;
        float u2 = (r + 2 < cnt) ? 1.f : 0.f;
        float u3 = (r + 3 < cnt) ? 1.f : 0.f;
        float t0 = fmaxf(d0 * 0.00390625f - 0.5f, 0.f);   // /256, DELTA_V
        float t1 = fmaxf(d1 * 0.00390625f - 0.5f, 0.f);
        float t2 = fmaxf(d2 * 0.00390625f - 0.5f, 0.f);
        float t3 = fmaxf(d3 * 0.00390625f - 0.5f, 0.f);
        psum += u0*t0*t0 + u1*t1*t1 + u2*t2*t2 + u3*t3*t3;
    }
    if (lane == 0) wsum[wv] = psum;
    __syncthreads();
    if (tid == 0) {
        float tot = 0.f;
        #pragma unroll
        for (int w = 0; w < 16; w++) tot += wsum[w];
        atomicAdd(&Lpull[seg >> 6], tot * ic);
    }
}

// ---------------- k5: push (128 blocks) + ticketed final combine ----------------
__global__ void k_final(const float* __restrict__ mus, const int* __restrict__ counts,
                        float* __restrict__ pushv, float* __restrict__ Lpull,
                        const float* __restrict__ Mvals, int* __restrict__ ticket,
                        float* __restrict__ outv, int n) {
    __shared__ float lds[NLBL][DIM + 1];
    __shared__ float wsum[4];
    __shared__ int lastFlag;
    int s = blockIdx.x >> 4;
    int chunk = blockIdx.x & 15;
    for (int i = threadIdx.x; i < NLBL * DIM; i += 256) {
        int r = i >> 8, d = i & 255;
        lds[r][d] = mus[(size_t)(s * NLBL + r) * DIM + d];
    }
    __syncthreads();
    int pair = chunk * 256 + threadIdx.x;
    int l1 = pair >> 6, l2 = pair & 63;
    float dist = 0.0f;
    #pragma unroll 8
    for (int d = 0; d < DIM; d++) dist += fabsf(lds[l1][d] - lds[l2][d]);
    float v = fmaxf(3.0f - dist, 0.0f);   // 2*DELTA_D
    v = v * v;
    bool ok = (l1 != l2) && (counts[s * NLBL + l1] > 0) && (counts[s * NLBL + l2] > 0);
    v = ok ? v : 0.0f;
    #pragma unroll
    for (int m = 32; m >= 1; m >>= 1) v += __shfl_xor(v, m, 64);
    if ((threadIdx.x & 63) == 0) wsum[threadIdx.x >> 6] = v;
    __syncthreads();
    if (threadIdx.x == 0) {
        atomicAdd(&pushv[s], wsum[0] + wsum[1] + wsum[2] + wsum[3]);
        __threadfence();
        int t = atomicAdd(ticket, 1);
        lastFlag = (t == (int)gridDim.x - 1) ? 1 : 0;
    }
    __syncthreads();
    if (lastFlag && threadIdx.x == 0) {
        float loss = 0.0f;
        for (int q = 0; q < NSB; q++) {
            float M = Mvals[q];
            float pv = atomicAdd(&pushv[q], 0.0f);    // coherent cross-XCD read
            float lpv = atomicAdd(&Lpull[q], 0.0f);
            if (M > 1.0f)
                loss += lpv / M + pv / fmaxf(M * (M - 1.0f), 1.0f);
        }
        outv[0] = loss / (float)n;
    }
}

extern "C" void kernel_launch(void* const* d_in, const int* in_sizes, int n_in,
                              void* d_out, int out_size, void* d_ws, size_t ws_size,
                              hipStream_t stream) {
    const float* outp = (const float*)d_in[0];
    const int* labels = (const int*)d_in[1];
    const int* sbidx = (const int*)d_in[2];
    float* outv = (float*)d_out;
    int n = in_sizes[1];

    int capTotal = n + NSEG * 64;   // aligned segment capacities upper bound

    // workspace layout
    unsigned* xq = (unsigned*)d_ws;                       // capTotal*64 dwords (~75 MB)
    float* mus = (float*)(xq + (size_t)capTotal * 64);    // NSEG*DIM
    int* sorted = (int*)(mus + (size_t)NSEG * DIM);       // capTotal
    int* blockBins = sorted + capTotal;                   // NBH*NSEG
    int* counts = blockBins + NBH * NSEG;                 // 512
    int* offsets = counts + NSEG;                         // 512
    int* cursors = offsets + NSEG;                        // 512
    int* ticket = cursors + NSEG;                         // 1
    float* invcnt = (float*)(ticket + 1);                 // 512
    float* Mvals = invcnt + NSEG;                         // 8
    float* Lpull = Mvals + NSB;                           // 8
    float* pushv = Lpull + NSB;                           // 8

    k_hist<<<NBH, 256, 0, stream>>>(labels, sbidx, blockBins, n);
    k_scan<<<1, 512, 0, stream>>>(blockBins, counts, offsets, cursors, Mvals, invcnt,
                                  Lpull, pushv, ticket);
    k_scatter<<<256, 256, 0, stream>>>(labels, sbidx, cursors, sorted, n);
    k_seg<<<NSEG, 1024, 0, stream>>>(outp, sorted, offsets, counts, invcnt,
                                     xq, mus, Lpull, n);
    k_final<<<NSB * 16, 256, 0, stream>>>(mus, counts, pushv, Lpull, Mvals,
                                          ticket, outv, n);
}

// Round 14
// 192.964 us; speedup vs baseline: 1.1275x; 1.0877x over previous
//
#include <hip/hip_runtime.h>

#define DIM 256
#define NSB 8
#define NLBL 64
#define NSEG (NSB * NLBL)
#define NBH 128   // histogram blocks
#define CAP 576   // staged rows per segment (LDS int8)
// dynamic LDS: xrows CAP*256B + muA 256*4 + wsum 16*4
#define SMEM_BYTES (CAP * 256 + DIM * 4 + 16 * 4)

// ---- k1: histogram (LDS bins -> global atomics) + fused last-block scan/init (R3 pattern) ----
__global__ void k_histscan(const int* __restrict__ labels, const int* __restrict__ sbidx,
                           int* __restrict__ counts, int* __restrict__ done,
                           int* __restrict__ offsets, int* __restrict__ cursors,
                           float* __restrict__ Mvals, float* __restrict__ invcnt,
                           float* __restrict__ Lpull, float* __restrict__ pushv,
                           int* __restrict__ ticket, int n) {
    __shared__ int bins[NSEG];
    __shared__ int lastFlag;
    for (int i = threadIdx.x; i < NSEG; i += 256) bins[i] = 0;
    __syncthreads();
    int t4 = blockIdx.x * 256 + threadIdx.x;
    int stride4 = gridDim.x * 256;
    for (int q = t4; q * 4 < n; q += stride4) {
        int4 lb = reinterpret_cast<const int4*>(labels)[q];
        int4 sb = reinterpret_cast<const int4*>(sbidx)[q];
        atomicAdd(&bins[sb.x * NLBL + lb.x], 1);
        atomicAdd(&bins[sb.y * NLBL + lb.y], 1);
        atomicAdd(&bins[sb.z * NLBL + lb.z], 1);
        atomicAdd(&bins[sb.w * NLBL + lb.w], 1);
    }
    __syncthreads();
    for (int i = threadIdx.x; i < NSEG; i += 256)
        if (bins[i] > 0) atomicAdd(&counts[i], bins[i]);
    __syncthreads();
    if (threadIdx.x == 0) {
        __threadfence();
        int t = atomicAdd(done, 1);
        lastFlag = (t == (int)gridDim.x - 1) ? 1 : 0;
    }
    __syncthreads();
    if (!lastFlag) return;
    // last block: coherent-read counts, scan, init all small buffers
    if (threadIdx.x < NSB) { Lpull[threadIdx.x] = 0.f; pushv[threadIdx.x] = 0.f; }
    if (threadIdx.x == 0) ticket[0] = 0;
    if (threadIdx.x < 64) {
        int lane = threadIdx.x;
        int carry = 0;
        for (int c = 0; c < NSB; c++) {
            int idx = c * 64 + lane;
            int v = atomicAdd(&counts[idx], 0);   // coherent cross-XCD read
            invcnt[idx] = 1.0f / fmaxf((float)v, 1.0f);
            int incl = v;
            #pragma unroll
            for (int m = 1; m < 64; m <<= 1) {
                int t2 = __shfl_up(incl, m, 64);
                if (lane >= m) incl += t2;
            }
            int excl = carry + incl - v;
            offsets[idx] = excl;
            cursors[idx] = excl;
            carry += __shfl(incl, 63, 64);
            unsigned long long b = __ballot(v > 0);
            if (lane == 0) Mvals[c] = (float)__popcll(b);
        }
    }
}

// ---------------- k2: scatter point indices into sorted order ----------------
__global__ void k_scatter(const int* __restrict__ labels, const int* __restrict__ sbidx,
                          int* __restrict__ cursors, int* __restrict__ sorted, int n) {
    int t = blockIdx.x * blockDim.x + threadIdx.x;
    int stride = gridDim.x * blockDim.x;
    for (int q = t; q * 4 < n; q += stride) {
        int4 lb = reinterpret_cast<const int4*>(labels)[q];
        int4 sb = reinterpret_cast<const int4*>(sbidx)[q];
        int p = q * 4;
        sorted[atomicAdd(&cursors[sb.x * NLBL + lb.x], 1)] = p;
        sorted[atomicAdd(&cursors[sb.y * NLBL + lb.y], 1)] = p + 1;
        sorted[atomicAdd(&cursors[sb.z * NLBL + lb.z], 1)] = p + 2;
        sorted[atomicAdd(&cursors[sb.w * NLBL + lb.w], 1)] = p + 3;
    }
}

__device__ inline unsigned packq(float x, float y, float z, float w, float s) {
    int q0 = (int)rintf(x * s); q0 = max(-127, min(127, q0));
    int q1 = (int)rintf(y * s); q1 = max(-127, min(127, q1));
    int q2 = (int)rintf(z * s); q2 = max(-127, min(127, q2));
    int q3 = (int)rintf(w * s); q3 = max(-127, min(127, q3));
    return (unsigned)(q0 & 255) | ((unsigned)(q1 & 255) << 8) |
           ((unsigned)(q2 & 255) << 16) | ((unsigned)(q3 & 255) << 24);
}

// ------- k3: ONE 16-wave block per segment: gather+norm+mu (int8 LDS stage) then pull -------
__global__ __launch_bounds__(1024) void k_seg(
    const float* __restrict__ outp, const int* __restrict__ sorted,
    const int* __restrict__ offsets, const int* __restrict__ counts,
    const float* __restrict__ invcnt, float* __restrict__ mus,
    float* __restrict__ Lpull) {
    extern __shared__ unsigned char smem[];
    unsigned* xrows = (unsigned*)smem;                   // CAP rows * 64 dwords
    float* muA  = (float*)(smem + CAP * 256);            // 256 (atomic accum -> mu)
    float* wsum = (float*)(smem + CAP * 256 + DIM * 4);  // 16

    int seg = blockIdx.x;
    int base = offsets[seg], cnt = counts[seg];
    int tid = threadIdx.x, lane = tid & 63, wv = tid >> 6;   // 16 waves
    float ic = invcnt[seg];
    if (tid < DIM) muA[tid] = 0.f;
    __syncthreads();
    if (cnt == 0) {
        if (tid < DIM) mus[(size_t)seg * DIM + tid] = 0.f;
        return;
    }

    // ---- Phase A: gather rows, normalize, accumulate mu, stage int8 into LDS ----
    float4 acc = {0.f, 0.f, 0.f, 0.f};
    int r = wv * 4;
    int p0 = (r + 0 < cnt) ? sorted[base + r + 0] : -1;
    int p1 = (r + 1 < cnt) ? sorted[base + r + 1] : -1;
    int p2 = (r + 2 < cnt) ? sorted[base + r + 2] : -1;
    int p3 = (r + 3 < cnt) ? sorted[base + r + 3] : -1;
    for (; r < cnt; r += 64) {
        int nr = r + 64;
        int q0 = (nr + 0 < cnt) ? sorted[base + nr + 0] : -1;   // prefetch next ids
        int q1 = (nr + 1 < cnt) ? sorted[base + nr + 1] : -1;
        int q2 = (nr + 2 < cnt) ? sorted[base + nr + 2] : -1;
        int q3 = (nr + 3 < cnt) ? sorted[base + nr + 3] : -1;
        float4 v0 = {0.f,0.f,0.f,0.f}, v1 = {0.f,0.f,0.f,0.f};
        float4 v2 = {0.f,0.f,0.f,0.f}, v3 = {0.f,0.f,0.f,0.f};
        v0 = *reinterpret_cast<const float4*>(outp + (size_t)p0 * DIM + lane * 4);
        if (p1 >= 0) v1 = *reinterpret_cast<const float4*>(outp + (size_t)p1 * DIM + lane * 4);
        if (p2 >= 0) v2 = *reinterpret_cast<const float4*>(outp + (size_t)p2 * DIM + lane * 4);
        if (p3 >= 0) v3 = *reinterpret_cast<const float4*>(outp + (size_t)p3 * DIM + lane * 4);
        float s0 = v0.x*v0.x + v0.y*v0.y + v0.z*v0.z + v0.w*v0.w;
        float s1 = v1.x*v1.x + v1.y*v1.y + v1.z*v1.z + v1.w*v1.w;
        float s2 = v2.x*v2.x + v2.y*v2.y + v2.z*v2.z + v2.w*v2.w;
        float s3 = v3.x*v3.x + v3.y*v3.y + v3.z*v3.z + v3.w*v3.w;
        #pragma unroll
        for (int m = 32; m >= 1; m >>= 1) {   // 4 interleaved trees
            s0 += __shfl_xor(s0, m, 64);
            s1 += __shfl_xor(s1, m, 64);
            s2 += __shfl_xor(s2, m, 64);
            s3 += __shfl_xor(s3, m, 64);
        }
        float r0 = 1.0f / (sqrtf(s0) + 1e-8f);
        float r1 = 1.0f / (sqrtf(s1) + 1e-8f);
        float r2 = 1.0f / (sqrtf(s2) + 1e-8f);
        float r3 = 1.0f / (sqrtf(s3) + 1e-8f);
        // stage int8 rows (scale 256 folded into rn)
        if (r + 0 < CAP)            xrows[(r + 0) * 64 + lane] = packq(v0.x, v0.y, v0.z, v0.w, r0 * 256.f);
        if (p1 >= 0 && r + 1 < CAP) xrows[(r + 1) * 64 + lane] = packq(v1.x, v1.y, v1.z, v1.w, r1 * 256.f);
        if (p2 >= 0 && r + 2 < CAP) xrows[(r + 2) * 64 + lane] = packq(v2.x, v2.y, v2.z, v2.w, r2 * 256.f);
        if (p3 >= 0 && r + 3 < CAP) xrows[(r + 3) * 64 + lane] = packq(v3.x, v3.y, v3.z, v3.w, r3 * 256.f);
        acc.x += v0.x*r0 + v1.x*r1 + v2.x*r2 + v3.x*r3;   // invalid rows are zeros
        acc.y += v0.y*r0 + v1.y*r1 + v2.y*r2 + v3.y*r3;
        acc.z += v0.z*r0 + v1.z*r1 + v2.z*r2 + v3.z*r3;
        acc.w += v0.w*r0 + v1.w*r1 + v2.w*r2 + v3.w*r3;
        p0 = q0; p1 = q1; p2 = q2; p3 = q3;
    }
    // LDS-atomic mu reduction (16 adds per address)
    atomicAdd(&muA[lane * 4 + 0], acc.x);
    atomicAdd(&muA[lane * 4 + 1], acc.y);
    atomicAdd(&muA[lane * 4 + 2], acc.z);
    atomicAdd(&muA[lane * 4 + 3], acc.w);
    __syncthreads();
    if (tid < DIM) {
        float mu = muA[tid] * ic;
        muA[tid] = mu;
        mus[(size_t)seg * DIM + tid] = mu;   // for the push kernel
    }
    __syncthreads();

    // ---- Phase B: pull from LDS (int8), mu in registers ----
    float4 mu4 = *reinterpret_cast<const float4*>(muA + lane * 4);
    float4 mu256 = {mu4.x * 256.f, mu4.y * 256.f, mu4.z * 256.f, mu4.w * 256.f};
    float psum = 0.f;
    int m1 = min(cnt, CAP);
    for (int rr = wv * 4; rr < m1; rr += 64) {
        bool b1 = rr + 1 < m1, b2 = rr + 2 < m1, b3 = rr + 3 < m1;
        unsigned w0 = xrows[(rr + 0) * 64 + lane];
        unsigned w1 = b1 ? xrows[(rr + 1) * 64 + lane] : 0u;
        unsigned w2 = b2 ? xrows[(rr + 2) * 64 + lane] : 0u;
        unsigned w3 = b3 ? xrows[(rr + 3) * 64 + lane] : 0u;
        float d0 = fabsf(mu256.x - (float)((int)(w0 << 24) >> 24))
                 + fabsf(mu256.y - (float)((int)(w0 << 16) >> 24))
                 + fabsf(mu256.z - (float)((int)(w0 <<  8) >> 24))
                 + fabsf(mu256.w - (float)((int)w0 >> 24));
        float d1 = fabsf(mu256.x - (float)((int)(w1 << 24) >> 24))
                 + fabsf(mu256.y - (float)((int)(w1 << 16) >> 24))
                 + fabsf(mu256.z - (float)((int)(w1 <<  8) >> 24))
                 + fabsf(mu256.w - (float)((int)w1 >> 24));
        float d2 = fabsf(mu256.x - (float)((int)(w2 << 24) >> 24))
                 + fabsf(mu256.y - (float)((int)(w2 << 16) >> 24))
                 + fabsf(mu256.z - (float)((int)(w2 <<  8) >> 24))
                 + fabsf(mu256.w - (float)((int)w2 >> 24));
        float d3 = fabsf(mu256.x - (float)((int)(w3 << 24) >> 24))
                 + fabsf(mu256.y - (float)((int)(w3 << 16) >> 24))
                 + fabsf(mu256.z - (float)((int)(w3 <<  8) >> 24))
                 + fabsf(mu256.w - (float)((int)w3 >> 24));
        #pragma unroll
        for (int m = 32; m >= 1; m >>= 1) {   // 4 interleaved trees
            d0 += __shfl_xor(d0, m, 64);
            d1 += __shfl_xor(d1, m, 64);
            d2 += __shfl_xor(d2, m, 64);
            d3 += __shfl_xor(d3, m, 64);
        }
        float t0 = fmaxf(d0 * 0.00390625f - 0.5f, 0.f);   // /256, DELTA_V
        psum += t0 * t0;
        if (b1) { float t = fmaxf(d1 * 0.00390625f - 0.5f, 0.f); psum += t * t; }
        if (b2) { float t = fmaxf(d2 * 0.00390625f - 0.5f, 0.f); psum += t * t; }
        if (b3) { float t = fmaxf(d3 * 0.00390625f - 0.5f, 0.f); psum += t * t; }
    }
    // overflow rows (cnt > CAP): re-gather from HBM, exact recompute (rare)
    for (int rr = CAP + wv; rr < cnt; rr += 16) {
        int p = sorted[base + rr];
        float4 v = *reinterpret_cast<const float4*>(outp + (size_t)p * DIM + lane * 4);
        float ss = v.x*v.x + v.y*v.y + v.z*v.z + v.w*v.w;
        #pragma unroll
        for (int m = 32; m >= 1; m >>= 1) ss += __shfl_xor(ss, m, 64);
        float rn = 1.0f / (sqrtf(ss) + 1e-8f);
        float d = fabsf(mu4.x - v.x*rn) + fabsf(mu4.y - v.y*rn)
                + fabsf(mu4.z - v.z*rn) + fabsf(mu4.w - v.w*rn);
        #pragma unroll
        for (int m = 32; m >= 1; m >>= 1) d += __shfl_xor(d, m, 64);
        float t = fmaxf(d - 0.5f, 0.f);
        psum += t * t;
    }
    if (lane == 0) wsum[wv] = psum;
    __syncthreads();
    if (tid == 0) {
        float tot = 0.f;
        #pragma unroll
        for (int w = 0; w < 16; w++) tot += wsum[w];
        atomicAdd(&Lpull[seg >> 6], tot * ic);
    }
}

// ---------------- k4: push (128 blocks) + ticketed final combine ----------------
__global__ void k_final(const float* __restrict__ mus, const int* __restrict__ counts,
                        float* __restrict__ pushv, float* __restrict__ Lpull,
                        const float* __restrict__ Mvals, int* __restrict__ ticket,
                        float* __restrict__ outv, int n) {
    __shared__ float lds[NLBL][DIM + 1];
    __shared__ float wsum[4];
    __shared__ int lastFlag;
    int s = blockIdx.x >> 4;
    int chunk = blockIdx.x & 15;
    for (int i = threadIdx.x; i < NLBL * DIM; i += 256) {
        int r = i >> 8, d = i & 255;
        lds[r][d] = mus[(size_t)(s * NLBL + r) * DIM + d];
    }
    __syncthreads();
    int pair = chunk * 256 + threadIdx.x;
    int l1 = pair >> 6, l2 = pair & 63;
    float dist = 0.0f;
    #pragma unroll 8
    for (int d = 0; d < DIM; d++) dist += fabsf(lds[l1][d] - lds[l2][d]);
    float v = fmaxf(3.0f - dist, 0.0f);   // 2*DELTA_D
    v = v * v;
    bool ok = (l1 != l2) && (counts[s * NLBL + l1] > 0) && (counts[s * NLBL + l2] > 0);
    v = ok ? v : 0.0f;
    #pragma unroll
    for (int m = 32; m >= 1; m >>= 1) v += __shfl_xor(v, m, 64);
    if ((threadIdx.x & 63) == 0) wsum[threadIdx.x >> 6] = v;
    __syncthreads();
    if (threadIdx.x == 0) {
        atomicAdd(&pushv[s], wsum[0] + wsum[1] + wsum[2] + wsum[3]);
        __threadfence();
        int t = atomicAdd(ticket, 1);
        lastFlag = (t == (int)gridDim.x - 1) ? 1 : 0;
    }
    __syncthreads();
    if (lastFlag && threadIdx.x == 0) {
        float loss = 0.0f;
        for (int q = 0; q < NSB; q++) {
            float M = Mvals[q];
            float pv = atomicAdd(&pushv[q], 0.0f);    // coherent cross-XCD read
            float lpv = atomicAdd(&Lpull[q], 0.0f);
            if (M > 1.0f)
                loss += lpv / M + pv / fmaxf(M * (M - 1.0f), 1.0f);
        }
        outv[0] = loss / (float)n;
    }
}

extern "C" void kernel_launch(void* const* d_in, const int* in_sizes, int n_in,
                              void* d_out, int out_size, void* d_ws, size_t ws_size,
                              hipStream_t stream) {
    const float* outp = (const float*)d_in[0];
    const int* labels = (const int*)d_in[1];
    const int* sbidx = (const int*)d_in[2];
    float* outv = (float*)d_out;
    int n = in_sizes[1];

    // workspace layout
    float* mus = (float*)d_ws;                            // NSEG*DIM
    int* sorted = (int*)(mus + (size_t)NSEG * DIM);       // n
    int* counts = sorted + n;                             // 512  -- zeroed
    int* done = counts + NSEG;                            // 1    -- zeroed
    int* offsets = done + 1;                              // 512
    int* cursors = offsets + NSEG;                        // 512
    int* ticket = cursors + NSEG;                         // 1
    float* invcnt = (float*)(ticket + 1);                 // 512
    float* Mvals = invcnt + NSEG;                         // 8
    float* Lpull = Mvals + NSB;                           // 8
    float* pushv = Lpull + NSB;                           // 8

    hipFuncSetAttribute(reinterpret_cast<const void*>(k_seg),
                        hipFuncAttributeMaxDynamicSharedMemorySize, SMEM_BYTES);

    hipMemsetAsync(counts, 0, (NSEG + 1) * 4, stream);   // counts + done
    k_histscan<<<NBH, 256, 0, stream>>>(labels, sbidx, counts, done, offsets, cursors,
                                        Mvals, invcnt, Lpull, pushv, ticket, n);
    k_scatter<<<512, 256, 0, stream>>>(labels, sbidx, cursors, sorted, n);
    k_seg<<<NSEG, 1024, SMEM_BYTES, stream>>>(outp, sorted, offsets, counts, invcnt,
                                              mus, Lpull);
    k_final<<<NSB * 16, 256, 0, stream>>>(mus, counts, pushv, Lpull, Mvals,
                                          ticket, outv, n);
}